// Round 8
// baseline (684.015 us; speedup 1.0000x reference)
//
#include <hip/hip_runtime.h>
#include <hip/hip_cooperative_groups.h>

namespace cg = cooperative_groups;

#define ST 512            // block threads (8 waves -> 2 blocks/CU co-resident)
#define PT 20             // edges per sort thread
#define EPB (ST * PT)     // 10240 edges per sort block
#define CSHIFT 9          // bucket = col >> 9 (width 512)
#define CMASK 511u
#define CW 512            // bucket width == block threads
#define CAP 12288         // slots/bucket (mean ~10225, sigma ~101 -> 20 sigma slack)

// ==================== phase bodies (shared by mega + split fallback) ====================

__device__ __forceinline__ void sort_body(const int* __restrict__ row,
                                          const int* __restrict__ col,
                                          unsigned* __restrict__ gcur,
                                          unsigned* __restrict__ pack1,
                                          int E, int NC, int b, int t) {
    __shared__ unsigned cnt[CW];
    __shared__ unsigned cur[CW];
    cnt[t] = 0;
    __syncthreads();
    int base = b * EPB;
    int c[PT];
#pragma unroll
    for (int k = 0; k < PT / 4; ++k) {
        int e = base + (k * ST + t) * 4;
        int4 cc;
        if (e + 3 < E) {
            cc = *reinterpret_cast<const int4*>(col + e);
        } else {
            cc.x = (e     < E) ? col[e]     : -1;
            cc.y = (e + 1 < E) ? col[e + 1] : -1;
            cc.z = (e + 2 < E) ? col[e + 2] : -1;
            cc.w = (e + 3 < E) ? col[e + 3] : -1;
        }
        c[4 * k] = cc.x; c[4 * k + 1] = cc.y; c[4 * k + 2] = cc.z; c[4 * k + 3] = cc.w;
    }
#pragma unroll
    for (int k = 0; k < PT; ++k)
        if (c[k] >= 0) atomicAdd(&cnt[(unsigned)c[k] >> CSHIFT], 1u);
    __syncthreads();
    if (t < NC) cur[t] = atomicAdd(&gcur[t], cnt[t]);   // contiguous reservation
    __syncthreads();
#pragma unroll
    for (int k = 0; k < PT / 4; ++k) {
        int e = base + (k * ST + t) * 4;
        int4 rr = make_int4(0, 0, 0, 0);
        if (e + 3 < E) {
            rr = *reinterpret_cast<const int4*>(row + e);
        } else {
            rr.x = (e     < E) ? row[e]     : 0;
            rr.y = (e + 1 < E) ? row[e + 1] : 0;
            rr.z = (e + 2 < E) ? row[e + 2] : 0;
            rr.w = (e + 3 < E) ? row[e + 3] : 0;
        }
        int rl[4] = {rr.x, rr.y, rr.z, rr.w};
#pragma unroll
        for (int j = 0; j < 4; ++j) {
            int cc = c[4 * k + j];
            if (cc >= 0) {
                unsigned bb = (unsigned)cc >> CSHIFT;
                unsigned pos = atomicAdd(&cur[bb], 1u);
                if (pos < (bb + 1u) * CAP)  // 20-sigma overflow guard
                    pack1[pos] = ((unsigned)rl[j] << CSHIFT) | ((unsigned)cc & CMASK);
            }
        }
    }
}

__device__ __forceinline__ void deg_body(const unsigned* __restrict__ pack1,
                                         const float* __restrict__ x,
                                         float* __restrict__ dinv, float* __restrict__ xs,
                                         unsigned s0, unsigned s1, int N, int b, int t) {
    __shared__ unsigned dcnt[CW];
    dcnt[t] = 0;
    __syncthreads();
    unsigned n4 = (s1 - s0) >> 2;
    for (unsigned i = t; i < n4; i += ST) {
        uint4 p = reinterpret_cast<const uint4*>(pack1 + s0)[i];
        atomicAdd(&dcnt[p.x & CMASK], 1u);
        atomicAdd(&dcnt[p.y & CMASK], 1u);
        atomicAdd(&dcnt[p.z & CMASK], 1u);
        atomicAdd(&dcnt[p.w & CMASK], 1u);
    }
    unsigned i = s0 + (n4 << 2) + t;
    if (i < s1) atomicAdd(&dcnt[pack1[i] & CMASK], 1u);
    __syncthreads();
    int v = (b << CSHIFT) + t;
    if (v < N) {
        float di = rsqrtf((float)dcnt[t] + 1.0f);
        dinv[v] = di;
        xs[v] = di * x[v];
    }
}

__device__ __forceinline__ void l1_body(const unsigned* __restrict__ pack1,
                                        const float* __restrict__ xs,
                                        const float* __restrict__ dinv,
                                        const float* __restrict__ W1,
                                        const float* __restrict__ b1,
                                        const float* __restrict__ W2,
                                        float* __restrict__ gs,
                                        unsigned s0, unsigned s1, int N, int b, int t) {
    __shared__ float acc[CW];
    acc[t] = 0.0f;
    __syncthreads();
    unsigned n4 = (s1 - s0) >> 2;
    for (unsigned i = t; i < n4; i += ST) {
        uint4 p = reinterpret_cast<const uint4*>(pack1 + s0)[i];
        float v0 = xs[p.x >> CSHIFT];
        float v1 = xs[p.y >> CSHIFT];
        float v2 = xs[p.z >> CSHIFT];
        float v3 = xs[p.w >> CSHIFT];
        atomicAdd(&acc[p.x & CMASK], v0);
        atomicAdd(&acc[p.y & CMASK], v1);
        atomicAdd(&acc[p.z & CMASK], v2);
        atomicAdd(&acc[p.w & CMASK], v3);
    }
    unsigned i = s0 + (n4 << 2) + t;
    if (i < s1) {
        unsigned p = pack1[i];
        atomicAdd(&acc[p & CMASK], xs[p >> CSHIFT]);
    }
    __syncthreads();
    int v = (b << CSHIFT) + t;
    if (v < N) {
        float di = dinv[v];
        float tt = di * (acc[t] + xs[v]);  // + self-loop
        float g = 0.0f;
#pragma unroll
        for (int j = 0; j < 16; ++j) {
            float y = fmaxf(fmaf(W1[j], tt, b1[j]), 0.0f);
            g = fmaf(W2[2 * j] - W2[2 * j + 1], y, g);
        }
        gs[v] = di * g;
    }
}

__device__ __forceinline__ void l2_body(const unsigned* __restrict__ pack1,
                                        const float* __restrict__ gs,
                                        const float* __restrict__ dinv,
                                        const float* __restrict__ b2,
                                        float* __restrict__ out,
                                        unsigned s0, unsigned s1, int N, int b, int t) {
    __shared__ float acc[CW];
    acc[t] = 0.0f;
    __syncthreads();
    unsigned n4 = (s1 - s0) >> 2;
    for (unsigned i = t; i < n4; i += ST) {
        uint4 p = reinterpret_cast<const uint4*>(pack1 + s0)[i];
        float v0 = gs[p.x >> CSHIFT];
        float v1 = gs[p.y >> CSHIFT];
        float v2 = gs[p.z >> CSHIFT];
        float v3 = gs[p.w >> CSHIFT];
        atomicAdd(&acc[p.x & CMASK], v0);
        atomicAdd(&acc[p.y & CMASK], v1);
        atomicAdd(&acc[p.z & CMASK], v2);
        atomicAdd(&acc[p.w & CMASK], v3);
    }
    unsigned i = s0 + (n4 << 2) + t;
    if (i < s1) {
        unsigned p = pack1[i];
        atomicAdd(&acc[p & CMASK], gs[p >> CSHIFT]);
    }
    __syncthreads();
    int v = (b << CSHIFT) + t;
    if (v < N) {
        float diff = dinv[v] * (acc[t] + gs[v]) + (b2[0] - b2[1]);
        float p0 = 1.0f / (1.0f + __expf(-diff));
        float2 o;
        o.x = p0;
        o.y = 1.0f - p0;
        reinterpret_cast<float2*>(out)[v] = o;
    }
}

// ==================== cooperative mega-kernel ====================
__global__ __launch_bounds__(ST) void k_mega(const int* __restrict__ row,
                                             const int* __restrict__ col,
                                             const float* __restrict__ x,
                                             const float* __restrict__ W1,
                                             const float* __restrict__ b1,
                                             const float* __restrict__ W2,
                                             const float* __restrict__ b2,
                                             unsigned* __restrict__ gcur,
                                             unsigned* __restrict__ pack1,
                                             float* __restrict__ dinv,
                                             float* __restrict__ xs,
                                             float* __restrict__ gs,
                                             float* __restrict__ out,
                                             int E, int N, int NC) {
    cg::grid_group grid = cg::this_grid();
    const int b = blockIdx.x;
    const int t = threadIdx.x;

    // phase 0: init per-bucket cursors (ws is poisoned 0xAA)
    if (t == 0 && b < NC) gcur[b] = (unsigned)b * CAP;
    grid.sync();

    // phase S: reservation counting-sort
    sort_body(row, col, gcur, pack1, E, NC, b, t);
    __threadfence();
    grid.sync();

    unsigned s0 = 0, s1 = 0;
    if (b < NC) {
        s0 = (unsigned)b * CAP;
        s1 = min(gcur[b], s0 + (unsigned)CAP);
    }

    // phase D: degree -> dinv, xs
    if (b < NC) deg_body(pack1, x, dinv, xs, s0, s1, N, b, t);
    __threadfence();
    grid.sync();

    // phase L1: propagate xs + fused MLP collapse -> gs
    if (b < NC) l1_body(pack1, xs, dinv, W1, b1, W2, gs, s0, s1, N, b, t);
    __threadfence();
    grid.sync();

    // phase L2: propagate gs + sigmoid epilogue -> out
    if (b < NC) l2_body(pack1, gs, dinv, b2, out, s0, s1, N, b, t);
}

// ==================== split fallback (if cooperative launch refused) ====================
__global__ void k_init(unsigned* __restrict__ gcur, int NC) {
    for (int b = threadIdx.x + blockIdx.x * blockDim.x; b < NC; b += blockDim.x * gridDim.x)
        gcur[b] = (unsigned)b * CAP;
}
__global__ __launch_bounds__(ST) void k_sortk(const int* __restrict__ row,
                                              const int* __restrict__ col,
                                              unsigned* __restrict__ gcur,
                                              unsigned* __restrict__ pack1, int E, int NC) {
    sort_body(row, col, gcur, pack1, E, NC, blockIdx.x, threadIdx.x);
}
__global__ __launch_bounds__(ST) void k_degk(const unsigned* __restrict__ pack1,
                                             const unsigned* __restrict__ gcur,
                                             const float* __restrict__ x,
                                             float* __restrict__ dinv, float* __restrict__ xs,
                                             int N) {
    int b = blockIdx.x;
    unsigned s0 = (unsigned)b * CAP;
    unsigned s1 = min(gcur[b], s0 + (unsigned)CAP);
    deg_body(pack1, x, dinv, xs, s0, s1, N, b, threadIdx.x);
}
__global__ __launch_bounds__(ST) void k_l1k(const unsigned* __restrict__ pack1,
                                            const unsigned* __restrict__ gcur,
                                            const float* __restrict__ xs,
                                            const float* __restrict__ dinv,
                                            const float* __restrict__ W1,
                                            const float* __restrict__ b1,
                                            const float* __restrict__ W2,
                                            float* __restrict__ gs, int N) {
    int b = blockIdx.x;
    unsigned s0 = (unsigned)b * CAP;
    unsigned s1 = min(gcur[b], s0 + (unsigned)CAP);
    l1_body(pack1, xs, dinv, W1, b1, W2, gs, s0, s1, N, b, threadIdx.x);
}
__global__ __launch_bounds__(ST) void k_l2k(const unsigned* __restrict__ pack1,
                                            const unsigned* __restrict__ gcur,
                                            const float* __restrict__ gs,
                                            const float* __restrict__ dinv,
                                            const float* __restrict__ b2,
                                            float* __restrict__ out, int N) {
    int b = blockIdx.x;
    unsigned s0 = (unsigned)b * CAP;
    unsigned s1 = min(gcur[b], s0 + (unsigned)CAP);
    l2_body(pack1, gs, dinv, b2, out, s0, s1, N, b, threadIdx.x);
}

// ==================== generic fallback (R2 atomic path, any sizes) ====================
__global__ void k_zero_f(float* __restrict__ p, int n) {
    int i = blockIdx.x * blockDim.x + threadIdx.x;
    int v = i * 4;
    if (v + 3 < n) {
        reinterpret_cast<float4*>(p + v)[0] = make_float4(0.f, 0.f, 0.f, 0.f);
    } else {
        for (; v < n; ++v) p[v] = 0.0f;
    }
}
__global__ void k_deg_f(const int* __restrict__ col, float* __restrict__ deg, int E) {
    int i = blockIdx.x * blockDim.x + threadIdx.x;
    int e = i * 4;
    if (e + 3 < E) {
        int4 c = reinterpret_cast<const int4*>(col + e)[0];
        atomicAdd(deg + c.x, 1.0f); atomicAdd(deg + c.y, 1.0f);
        atomicAdd(deg + c.z, 1.0f); atomicAdd(deg + c.w, 1.0f);
    } else {
        for (; e < E; ++e) atomicAdd(deg + col[e], 1.0f);
    }
}
__global__ void k_node1_f(const float* __restrict__ x, float* __restrict__ degdinv,
                          float* __restrict__ xs, int N) {
    int v = blockIdx.x * blockDim.x + threadIdx.x;
    if (v < N) {
        float dinv = rsqrtf(degdinv[v] + 1.0f);
        degdinv[v] = dinv;
        xs[v] = dinv * x[v];
    }
}
__global__ void k_scat_f(const int* __restrict__ row, const int* __restrict__ col,
                         const float* __restrict__ src, float* __restrict__ acc, int E) {
    int i = blockIdx.x * blockDim.x + threadIdx.x;
    int e = i * 4;
    if (e + 3 < E) {
        int4 r = reinterpret_cast<const int4*>(row + e)[0];
        int4 c = reinterpret_cast<const int4*>(col + e)[0];
        float s0 = src[r.x], s1 = src[r.y], s2 = src[r.z], s3 = src[r.w];
        atomicAdd(acc + c.x, s0); atomicAdd(acc + c.y, s1);
        atomicAdd(acc + c.z, s2); atomicAdd(acc + c.w, s3);
    } else {
        for (; e < E; ++e) atomicAdd(acc + col[e], src[row[e]]);
    }
}
__global__ void k_mlp_f(const float* __restrict__ W1, const float* __restrict__ b1,
                        const float* __restrict__ W2, const float* __restrict__ dinv,
                        float* __restrict__ acc, float* __restrict__ xsgs, int N) {
    int v = blockIdx.x * blockDim.x + threadIdx.x;
    if (v < N) {
        float di = dinv[v];
        float t = di * (acc[v] + xsgs[v]);
        float g = 0.0f;
#pragma unroll
        for (int j = 0; j < 16; ++j) {
            float y = fmaxf(fmaf(W1[j], t, b1[j]), 0.0f);
            g = fmaf(W2[2 * j] - W2[2 * j + 1], y, g);
        }
        xsgs[v] = di * g;
        acc[v] = 0.0f;
    }
}
__global__ void k_out_f(const float* __restrict__ b2, const float* __restrict__ dinv,
                        const float* __restrict__ acc, const float* __restrict__ gs,
                        float* __restrict__ out, int N) {
    int v = blockIdx.x * blockDim.x + threadIdx.x;
    if (v < N) {
        float diff = dinv[v] * (acc[v] + gs[v]) + (b2[0] - b2[1]);
        float p0 = 1.0f / (1.0f + __expf(-diff));
        float2 o; o.x = p0; o.y = 1.0f - p0;
        reinterpret_cast<float2*>(out)[v] = o;
    }
}

extern "C" void kernel_launch(void* const* d_in, const int* in_sizes, int n_in,
                              void* d_out, int out_size, void* d_ws, size_t ws_size,
                              hipStream_t stream) {
    const float* x  = (const float*)d_in[0];
    const int* edge = (const int*)d_in[1];   // int64 in reference -> int32 in harness
    const float* W1 = (const float*)d_in[2];
    const float* b1 = (const float*)d_in[3];
    const float* W2 = (const float*)d_in[4];
    const float* b2 = (const float*)d_in[5];
    float* out = (float*)d_out;

    const int N = in_sizes[0];
    const int E = in_sizes[1] / 2;
    const int* row = edge;       // sources
    const int* col = edge + E;   // targets

    const int NC  = (N + CW - 1) >> CSHIFT;            // buckets (489)
    const int NBS = (E + EPB - 1) / EPB;               // sort blocks (489)
    const int NB  = NC > NBS ? NC : NBS;

    // Capacity check: mean + 8 sigma must fit CAP.
    const double mean = (double)E / NC;
    const double slack = mean + 8.0 * __builtin_sqrt(mean > 1.0 ? mean : 1.0);
    // ws: pack1[NC*CAP] | gcur[NC] (ints) then dinv[N] | xs[N] | gs[N] (floats)
    const size_t need = ((size_t)NC * CAP + NC) * 4 + (size_t)3 * N * 4;

    if (NC <= CW && N < (1 << 23) && slack < CAP && ws_size >= need) {
        unsigned* pack1 = (unsigned*)d_ws;
        unsigned* gcur  = pack1 + (size_t)NC * CAP;
        float* dinv     = (float*)(gcur + NC);
        float* xs       = dinv + N;
        float* gs       = xs + N;

        void* args[] = {(void*)&row, (void*)&col, (void*)&x,
                        (void*)&W1, (void*)&b1, (void*)&W2, (void*)&b2,
                        (void*)&gcur, (void*)&pack1,
                        (void*)&dinv, (void*)&xs, (void*)&gs, (void*)&out,
                        (void*)&E, (void*)&N, (void*)&NC};
        hipError_t err = hipLaunchCooperativeKernel((const void*)k_mega, dim3(NB), dim3(ST),
                                                    args, 0, stream);
        if (err != hipSuccess) {
            // split-launch fallback (same memory layout, same bodies)
            k_init <<<1, 512, 0, stream>>>(gcur, NC);
            k_sortk<<<NBS, ST, 0, stream>>>(row, col, gcur, pack1, E, NC);
            k_degk <<<NC, ST, 0, stream>>>(pack1, gcur, x, dinv, xs, N);
            k_l1k  <<<NC, ST, 0, stream>>>(pack1, gcur, xs, dinv, W1, b1, W2, gs, N);
            k_l2k  <<<NC, ST, 0, stream>>>(pack1, gcur, gs, dinv, b2, out, N);
        }
    } else {
        // generic fallback: R2 atomic-scatter path
        float* w0 = (float*)d_ws;
        float* w1 = w0 + N;
        float* w2 = w1 + N;
        const int nb = (N + 255) / 256;
        const int eb = ((E + 3) / 4 + 255) / 256;
        const int zb = ((2 * N + 3) / 4 + 255) / 256;
        k_zero_f <<<zb, 256, 0, stream>>>(w0, 2 * N);
        k_deg_f  <<<eb, 256, 0, stream>>>(col, w0, E);
        k_node1_f<<<nb, 256, 0, stream>>>(x, w0, w2, N);
        k_scat_f <<<eb, 256, 0, stream>>>(row, col, w2, w1, E);
        k_mlp_f  <<<nb, 256, 0, stream>>>(W1, b1, W2, w0, w1, w2, N);
        k_scat_f <<<eb, 256, 0, stream>>>(row, col, w2, w1, E);
        k_out_f  <<<nb, 256, 0, stream>>>(b2, w0, w1, w2, out, N);
    }
}

// Round 9
// 194.410 us; speedup vs baseline: 3.5184x; 3.5184x over previous
//
#include <hip/hip_runtime.h>

#define ST 512            // block threads (8 waves -> 2 blocks/CU co-resident)
#define PT 20             // edges per sort thread
#define EPB (ST * PT)     // 10240 edges per sort block
#define CSHIFT 9          // bucket = col >> 9 (width 512)
#define CMASK 511u
#define CW 512            // bucket width == block threads
#define CAP 12288         // slots/bucket (mean ~10225, sigma ~101 -> 20 sigma slack)

// ==================== phase bodies ====================

__device__ __forceinline__ void sort_body(const int* __restrict__ row,
                                          const int* __restrict__ col,
                                          unsigned* __restrict__ gcur,
                                          unsigned* __restrict__ pack1,
                                          int E, int NC, int b, int t) {
    __shared__ unsigned cnt[CW];
    __shared__ unsigned cur[CW];
    cnt[t] = 0;
    __syncthreads();
    int base = b * EPB;
    int c[PT];
#pragma unroll
    for (int k = 0; k < PT / 4; ++k) {
        int e = base + (k * ST + t) * 4;
        int4 cc;
        if (e + 3 < E) {
            cc = *reinterpret_cast<const int4*>(col + e);
        } else {
            cc.x = (e     < E) ? col[e]     : -1;
            cc.y = (e + 1 < E) ? col[e + 1] : -1;
            cc.z = (e + 2 < E) ? col[e + 2] : -1;
            cc.w = (e + 3 < E) ? col[e + 3] : -1;
        }
        c[4 * k] = cc.x; c[4 * k + 1] = cc.y; c[4 * k + 2] = cc.z; c[4 * k + 3] = cc.w;
    }
#pragma unroll
    for (int k = 0; k < PT; ++k)
        if (c[k] >= 0) atomicAdd(&cnt[(unsigned)c[k] >> CSHIFT], 1u);
    __syncthreads();
    if (t < NC) cur[t] = atomicAdd(&gcur[t], cnt[t]);   // contiguous reservation
    __syncthreads();
#pragma unroll
    for (int k = 0; k < PT / 4; ++k) {
        int e = base + (k * ST + t) * 4;
        int4 rr = make_int4(0, 0, 0, 0);
        if (e + 3 < E) {
            rr = *reinterpret_cast<const int4*>(row + e);
        } else {
            rr.x = (e     < E) ? row[e]     : 0;
            rr.y = (e + 1 < E) ? row[e + 1] : 0;
            rr.z = (e + 2 < E) ? row[e + 2] : 0;
            rr.w = (e + 3 < E) ? row[e + 3] : 0;
        }
        int rl[4] = {rr.x, rr.y, rr.z, rr.w};
#pragma unroll
        for (int j = 0; j < 4; ++j) {
            int cc = c[4 * k + j];
            if (cc >= 0) {
                unsigned bb = (unsigned)cc >> CSHIFT;
                unsigned pos = atomicAdd(&cur[bb], 1u);
                if (pos < (bb + 1u) * CAP)  // 20-sigma overflow guard
                    pack1[pos] = ((unsigned)rl[j] << CSHIFT) | ((unsigned)cc & CMASK);
            }
        }
    }
}

__device__ __forceinline__ void deg_body(const unsigned* __restrict__ pack1,
                                         const float* __restrict__ x,
                                         float* __restrict__ dinv, float* __restrict__ xs,
                                         unsigned s0, unsigned s1, int N, int b, int t) {
    __shared__ unsigned dcnt[CW];
    dcnt[t] = 0;
    __syncthreads();
    unsigned n4 = (s1 - s0) >> 2;
    for (unsigned i = t; i < n4; i += ST) {
        uint4 p = reinterpret_cast<const uint4*>(pack1 + s0)[i];
        atomicAdd(&dcnt[p.x & CMASK], 1u);
        atomicAdd(&dcnt[p.y & CMASK], 1u);
        atomicAdd(&dcnt[p.z & CMASK], 1u);
        atomicAdd(&dcnt[p.w & CMASK], 1u);
    }
    unsigned i = s0 + (n4 << 2) + t;
    if (i < s1) atomicAdd(&dcnt[pack1[i] & CMASK], 1u);
    __syncthreads();
    int v = (b << CSHIFT) + t;
    if (v < N) {
        float di = rsqrtf((float)dcnt[t] + 1.0f);
        dinv[v] = di;
        xs[v] = di * x[v];
    }
}

__device__ __forceinline__ void l1_body(const unsigned* __restrict__ pack1,
                                        const float* __restrict__ xs,
                                        const float* __restrict__ dinv,
                                        const float* __restrict__ W1,
                                        const float* __restrict__ b1,
                                        const float* __restrict__ W2,
                                        float* __restrict__ gs,
                                        unsigned s0, unsigned s1, int N, int b, int t) {
    __shared__ float acc[CW];
    acc[t] = 0.0f;
    __syncthreads();
    unsigned n4 = (s1 - s0) >> 2;
    for (unsigned i = t; i < n4; i += ST) {
        uint4 p = reinterpret_cast<const uint4*>(pack1 + s0)[i];
        float v0 = xs[p.x >> CSHIFT];
        float v1 = xs[p.y >> CSHIFT];
        float v2 = xs[p.z >> CSHIFT];
        float v3 = xs[p.w >> CSHIFT];
        atomicAdd(&acc[p.x & CMASK], v0);
        atomicAdd(&acc[p.y & CMASK], v1);
        atomicAdd(&acc[p.z & CMASK], v2);
        atomicAdd(&acc[p.w & CMASK], v3);
    }
    unsigned i = s0 + (n4 << 2) + t;
    if (i < s1) {
        unsigned p = pack1[i];
        atomicAdd(&acc[p & CMASK], xs[p >> CSHIFT]);
    }
    __syncthreads();
    int v = (b << CSHIFT) + t;
    if (v < N) {
        float di = dinv[v];
        float tt = di * (acc[t] + xs[v]);  // + self-loop
        float g = 0.0f;
#pragma unroll
        for (int j = 0; j < 16; ++j) {
            float y = fmaxf(fmaf(W1[j], tt, b1[j]), 0.0f);
            g = fmaf(W2[2 * j] - W2[2 * j + 1], y, g);
        }
        gs[v] = di * g;
    }
}

__device__ __forceinline__ void l2_body(const unsigned* __restrict__ pack1,
                                        const float* __restrict__ gs,
                                        const float* __restrict__ dinv,
                                        const float* __restrict__ b2,
                                        float* __restrict__ out,
                                        unsigned s0, unsigned s1, int N, int b, int t) {
    __shared__ float acc[CW];
    acc[t] = 0.0f;
    __syncthreads();
    unsigned n4 = (s1 - s0) >> 2;
    for (unsigned i = t; i < n4; i += ST) {
        uint4 p = reinterpret_cast<const uint4*>(pack1 + s0)[i];
        float v0 = gs[p.x >> CSHIFT];
        float v1 = gs[p.y >> CSHIFT];
        float v2 = gs[p.z >> CSHIFT];
        float v3 = gs[p.w >> CSHIFT];
        atomicAdd(&acc[p.x & CMASK], v0);
        atomicAdd(&acc[p.y & CMASK], v1);
        atomicAdd(&acc[p.z & CMASK], v2);
        atomicAdd(&acc[p.w & CMASK], v3);
    }
    unsigned i = s0 + (n4 << 2) + t;
    if (i < s1) {
        unsigned p = pack1[i];
        atomicAdd(&acc[p & CMASK], gs[p >> CSHIFT]);
    }
    __syncthreads();
    int v = (b << CSHIFT) + t;
    if (v < N) {
        float diff = dinv[v] * (acc[t] + gs[v]) + (b2[0] - b2[1]);
        float p0 = 1.0f / (1.0f + __expf(-diff));
        float2 o;
        o.x = p0;
        o.y = 1.0f - p0;
        reinterpret_cast<float2*>(out)[v] = o;
    }
}

// ==================== split kernels (kernel boundary = cheap device-wide sync) ====================
__global__ void k_init(unsigned* __restrict__ gcur, int NC) {
    for (int b = threadIdx.x + blockIdx.x * blockDim.x; b < NC; b += blockDim.x * gridDim.x)
        gcur[b] = (unsigned)b * CAP;
}
__global__ __launch_bounds__(ST) void k_sortk(const int* __restrict__ row,
                                              const int* __restrict__ col,
                                              unsigned* __restrict__ gcur,
                                              unsigned* __restrict__ pack1, int E, int NC) {
    sort_body(row, col, gcur, pack1, E, NC, blockIdx.x, threadIdx.x);
}
__global__ __launch_bounds__(ST) void k_degk(const unsigned* __restrict__ pack1,
                                             const unsigned* __restrict__ gcur,
                                             const float* __restrict__ x,
                                             float* __restrict__ dinv, float* __restrict__ xs,
                                             int N) {
    int b = blockIdx.x;
    unsigned s0 = (unsigned)b * CAP;
    unsigned s1 = min(gcur[b], s0 + (unsigned)CAP);
    deg_body(pack1, x, dinv, xs, s0, s1, N, b, threadIdx.x);
}
__global__ __launch_bounds__(ST) void k_l1k(const unsigned* __restrict__ pack1,
                                            const unsigned* __restrict__ gcur,
                                            const float* __restrict__ xs,
                                            const float* __restrict__ dinv,
                                            const float* __restrict__ W1,
                                            const float* __restrict__ b1,
                                            const float* __restrict__ W2,
                                            float* __restrict__ gs, int N) {
    int b = blockIdx.x;
    unsigned s0 = (unsigned)b * CAP;
    unsigned s1 = min(gcur[b], s0 + (unsigned)CAP);
    l1_body(pack1, xs, dinv, W1, b1, W2, gs, s0, s1, N, b, threadIdx.x);
}
__global__ __launch_bounds__(ST) void k_l2k(const unsigned* __restrict__ pack1,
                                            const unsigned* __restrict__ gcur,
                                            const float* __restrict__ gs,
                                            const float* __restrict__ dinv,
                                            const float* __restrict__ b2,
                                            float* __restrict__ out, int N) {
    int b = blockIdx.x;
    unsigned s0 = (unsigned)b * CAP;
    unsigned s1 = min(gcur[b], s0 + (unsigned)CAP);
    l2_body(pack1, gs, dinv, b2, out, s0, s1, N, b, threadIdx.x);
}

// ==================== generic fallback (R2 atomic path, any sizes) ====================
__global__ void k_zero_f(float* __restrict__ p, int n) {
    int i = blockIdx.x * blockDim.x + threadIdx.x;
    int v = i * 4;
    if (v + 3 < n) {
        reinterpret_cast<float4*>(p + v)[0] = make_float4(0.f, 0.f, 0.f, 0.f);
    } else {
        for (; v < n; ++v) p[v] = 0.0f;
    }
}
__global__ void k_deg_f(const int* __restrict__ col, float* __restrict__ deg, int E) {
    int i = blockIdx.x * blockDim.x + threadIdx.x;
    int e = i * 4;
    if (e + 3 < E) {
        int4 c = reinterpret_cast<const int4*>(col + e)[0];
        atomicAdd(deg + c.x, 1.0f); atomicAdd(deg + c.y, 1.0f);
        atomicAdd(deg + c.z, 1.0f); atomicAdd(deg + c.w, 1.0f);
    } else {
        for (; e < E; ++e) atomicAdd(deg + col[e], 1.0f);
    }
}
__global__ void k_node1_f(const float* __restrict__ x, float* __restrict__ degdinv,
                          float* __restrict__ xs, int N) {
    int v = blockIdx.x * blockDim.x + threadIdx.x;
    if (v < N) {
        float dinv = rsqrtf(degdinv[v] + 1.0f);
        degdinv[v] = dinv;
        xs[v] = dinv * x[v];
    }
}
__global__ void k_scat_f(const int* __restrict__ row, const int* __restrict__ col,
                         const float* __restrict__ src, float* __restrict__ acc, int E) {
    int i = blockIdx.x * blockDim.x + threadIdx.x;
    int e = i * 4;
    if (e + 3 < E) {
        int4 r = reinterpret_cast<const int4*>(row + e)[0];
        int4 c = reinterpret_cast<const int4*>(col + e)[0];
        float s0 = src[r.x], s1 = src[r.y], s2 = src[r.z], s3 = src[r.w];
        atomicAdd(acc + c.x, s0); atomicAdd(acc + c.y, s1);
        atomicAdd(acc + c.z, s2); atomicAdd(acc + c.w, s3);
    } else {
        for (; e < E; ++e) atomicAdd(acc + col[e], src[row[e]]);
    }
}
__global__ void k_mlp_f(const float* __restrict__ W1, const float* __restrict__ b1,
                        const float* __restrict__ W2, const float* __restrict__ dinv,
                        float* __restrict__ acc, float* __restrict__ xsgs, int N) {
    int v = blockIdx.x * blockDim.x + threadIdx.x;
    if (v < N) {
        float di = dinv[v];
        float t = di * (acc[v] + xsgs[v]);
        float g = 0.0f;
#pragma unroll
        for (int j = 0; j < 16; ++j) {
            float y = fmaxf(fmaf(W1[j], t, b1[j]), 0.0f);
            g = fmaf(W2[2 * j] - W2[2 * j + 1], y, g);
        }
        xsgs[v] = di * g;
        acc[v] = 0.0f;
    }
}
__global__ void k_out_f(const float* __restrict__ b2, const float* __restrict__ dinv,
                        const float* __restrict__ acc, const float* __restrict__ gs,
                        float* __restrict__ out, int N) {
    int v = blockIdx.x * blockDim.x + threadIdx.x;
    if (v < N) {
        float diff = dinv[v] * (acc[v] + gs[v]) + (b2[0] - b2[1]);
        float p0 = 1.0f / (1.0f + __expf(-diff));
        float2 o; o.x = p0; o.y = 1.0f - p0;
        reinterpret_cast<float2*>(out)[v] = o;
    }
}

extern "C" void kernel_launch(void* const* d_in, const int* in_sizes, int n_in,
                              void* d_out, int out_size, void* d_ws, size_t ws_size,
                              hipStream_t stream) {
    const float* x  = (const float*)d_in[0];
    const int* edge = (const int*)d_in[1];   // int64 in reference -> int32 in harness
    const float* W1 = (const float*)d_in[2];
    const float* b1 = (const float*)d_in[3];
    const float* W2 = (const float*)d_in[4];
    const float* b2 = (const float*)d_in[5];
    float* out = (float*)d_out;

    const int N = in_sizes[0];
    const int E = in_sizes[1] / 2;
    const int* row = edge;       // sources
    const int* col = edge + E;   // targets

    const int NC  = (N + CW - 1) >> CSHIFT;            // buckets (489)
    const int NBS = (E + EPB - 1) / EPB;               // sort blocks (489)

    // Capacity check: mean + 8 sigma must fit CAP.
    const double mean = (double)E / NC;
    const double slack = mean + 8.0 * __builtin_sqrt(mean > 1.0 ? mean : 1.0);
    // ws: pack1[NC*CAP] | gcur[NC] (ints) then dinv[N] | xs[N] | gs[N] (floats)
    const size_t need = ((size_t)NC * CAP + NC) * 4 + (size_t)3 * N * 4;

    if (NC <= CW && N < (1 << 23) && slack < CAP && ws_size >= need) {
        unsigned* pack1 = (unsigned*)d_ws;
        unsigned* gcur  = pack1 + (size_t)NC * CAP;
        float* dinv     = (float*)(gcur + NC);
        float* xs       = dinv + N;
        float* gs       = xs + N;

        // Split launches: the kernel boundary is the cheap device-wide sync on
        // gfx950 (cooperative grid.sync forces per-block device-scope L2
        // flushes across non-coherent XCDs -> 3.5x regression, R8).
        k_init <<<1, 512, 0, stream>>>(gcur, NC);
        k_sortk<<<NBS, ST, 0, stream>>>(row, col, gcur, pack1, E, NC);
        k_degk <<<NC, ST, 0, stream>>>(pack1, gcur, x, dinv, xs, N);
        k_l1k  <<<NC, ST, 0, stream>>>(pack1, gcur, xs, dinv, W1, b1, W2, gs, N);
        k_l2k  <<<NC, ST, 0, stream>>>(pack1, gcur, gs, dinv, b2, out, N);
    } else {
        // generic fallback: R2 atomic-scatter path
        float* w0 = (float*)d_ws;
        float* w1 = w0 + N;
        float* w2 = w1 + N;
        const int nb = (N + 255) / 256;
        const int eb = ((E + 3) / 4 + 255) / 256;
        const int zb = ((2 * N + 3) / 4 + 255) / 256;
        k_zero_f <<<zb, 256, 0, stream>>>(w0, 2 * N);
        k_deg_f  <<<eb, 256, 0, stream>>>(col, w0, E);
        k_node1_f<<<nb, 256, 0, stream>>>(x, w0, w2, N);
        k_scat_f <<<eb, 256, 0, stream>>>(row, col, w2, w1, E);
        k_mlp_f  <<<nb, 256, 0, stream>>>(W1, b1, W2, w0, w1, w2, N);
        k_scat_f <<<eb, 256, 0, stream>>>(row, col, w2, w1, E);
        k_out_f  <<<nb, 256, 0, stream>>>(b2, w0, w1, w2, out, N);
    }
}

// Round 10
// 183.072 us; speedup vs baseline: 3.7363x; 1.0619x over previous
//
#include <hip/hip_runtime.h>

#define ST 512            // block threads (8 waves)
#define PT 20             // edges per sort thread
#define EPB (ST * PT)     // 10240 edges per sort block
#define CSHIFT 10         // bucket = col >> 10 (width 1024)
#define CMASK 1023u
#define CW 1024           // bucket width for deg/l1/l2 LDS arrays
#define NCMAX 256         // max buckets supported by sort LDS arrays
#define CAP 24576         // slots/bucket (mean 20408, sigma ~143 -> 29 sigma slack)

// ==================== LDS-staged counting sort ====================
// pack1 = (row << 10) | (col & 1023)   [requires N < 2^22]
// bucket b owns pack1[b*CAP .. gcur[b]) after k_sortk.

__global__ void k_init(unsigned* __restrict__ gcur, int NC) {
    for (int b = threadIdx.x; b < NC; b += blockDim.x)
        gcur[b] = (unsigned)b * CAP;
}

__global__ __launch_bounds__(ST) void k_sortk(const int* __restrict__ row,
                                              const int* __restrict__ col,
                                              unsigned* __restrict__ gcur,
                                              unsigned* __restrict__ pack1,
                                              int E, int NC) {
    __shared__ unsigned loff[NCMAX + 1];   // hist -> exclusive offsets (kept for copy-out)
    __shared__ unsigned gbase[NCMAX];      // per-bucket global reservation base
    __shared__ unsigned cur[NCMAX];        // staging placement cursors
    __shared__ unsigned staging[EPB];      // 40 KB packed edges, bucket-grouped

    const int t = threadIdx.x;
    for (int i = t; i <= NC; i += ST) loff[i] = 0;
    __syncthreads();

    const int base = blockIdx.x * EPB;
    int c[PT];

    // ---- load col (kept in registers), histogram into loff[b+1] ----
#pragma unroll
    for (int k = 0; k < PT / 4; ++k) {
        int e = base + (k * ST + t) * 4;
        int4 cc;
        if (e + 3 < E) {
            cc = *reinterpret_cast<const int4*>(col + e);
        } else {
            cc.x = (e     < E) ? col[e]     : -1;
            cc.y = (e + 1 < E) ? col[e + 1] : -1;
            cc.z = (e + 2 < E) ? col[e + 2] : -1;
            cc.w = (e + 3 < E) ? col[e + 3] : -1;
        }
        c[4 * k] = cc.x; c[4 * k + 1] = cc.y; c[4 * k + 2] = cc.z; c[4 * k + 3] = cc.w;
    }
#pragma unroll
    for (int k = 0; k < PT; ++k)
        if (c[k] >= 0) atomicAdd(&loff[((unsigned)c[k] >> CSHIFT) + 1], 1u);
    __syncthreads();

    // ---- inclusive scan of loff[0..NC] -> loff[b] = exclusive offset of bucket b ----
    for (int o = 1; o <= NC; o <<= 1) {
        unsigned v = 0;
        if (t <= NC && t >= o) v = loff[t - o];
        __syncthreads();
        if (t <= NC) loff[t] += v;
        __syncthreads();
    }

    // ---- per-bucket contiguous global reservation ----
    if (t < NC) {
        unsigned cb = loff[t + 1] - loff[t];
        gbase[t] = atomicAdd(&gcur[t], cb);
        cur[t] = loff[t];
    }
    __syncthreads();

    // ---- place packed edges into LDS staging (bucket-grouped) ----
#pragma unroll
    for (int k = 0; k < PT / 4; ++k) {
        int e = base + (k * ST + t) * 4;
        int4 rr = make_int4(0, 0, 0, 0);
        if (e + 3 < E) {
            rr = *reinterpret_cast<const int4*>(row + e);
        } else {
            rr.x = (e     < E) ? row[e]     : 0;
            rr.y = (e + 1 < E) ? row[e + 1] : 0;
            rr.z = (e + 2 < E) ? row[e + 2] : 0;
            rr.w = (e + 3 < E) ? row[e + 3] : 0;
        }
        int rl[4] = {rr.x, rr.y, rr.z, rr.w};
#pragma unroll
        for (int j = 0; j < 4; ++j) {
            int cc = c[4 * k + j];
            if (cc >= 0) {
                unsigned b = (unsigned)cc >> CSHIFT;
                unsigned p = atomicAdd(&cur[b], 1u);
                staging[p] = ((unsigned)rl[j] << CSHIFT) | ((unsigned)cc & CMASK);
            }
        }
    }
    __syncthreads();

    // ---- coalesced copy-out: thread i -> global gbase[b] + (i - loff[b]) ----
    const unsigned tot = loff[NC];
    for (unsigned i = t; i < tot; i += ST) {
        unsigned lo = 0, hi = (unsigned)NC;          // find b: loff[b] <= i < loff[b+1]
        while (hi - lo > 1) {
            unsigned mid = (lo + hi) >> 1;
            if (loff[mid] <= i) lo = mid; else hi = mid;
        }
        unsigned pos = gbase[lo] + (i - loff[lo]);
        if (pos < (lo + 1u) * CAP)                    // 29-sigma overflow guard
            pack1[pos] = staging[i];
    }
}

// ==================== per-bucket kernels (1024-wide buckets, 512 threads) ====================

__global__ __launch_bounds__(ST) void k_degk(const unsigned* __restrict__ pack1,
                                             const unsigned* __restrict__ gcur,
                                             const float* __restrict__ x,
                                             float* __restrict__ dinv, float* __restrict__ xs,
                                             int N) {
    __shared__ unsigned dcnt[CW];
    const int b = blockIdx.x;
    const int t = threadIdx.x;
    dcnt[t] = 0; dcnt[t + ST] = 0;
    __syncthreads();
    unsigned s0 = (unsigned)b * CAP;
    unsigned s1 = min(gcur[b], s0 + (unsigned)CAP);
    unsigned n4 = (s1 - s0) >> 2;
    for (unsigned i = t; i < n4; i += ST) {
        uint4 p = reinterpret_cast<const uint4*>(pack1 + s0)[i];
        atomicAdd(&dcnt[p.x & CMASK], 1u);
        atomicAdd(&dcnt[p.y & CMASK], 1u);
        atomicAdd(&dcnt[p.z & CMASK], 1u);
        atomicAdd(&dcnt[p.w & CMASK], 1u);
    }
    unsigned i = s0 + (n4 << 2) + t;
    if (i < s1) atomicAdd(&dcnt[pack1[i] & CMASK], 1u);
    __syncthreads();
#pragma unroll
    for (int j = 0; j < 2; ++j) {
        int tl = t + j * ST;
        int v = (b << CSHIFT) + tl;
        if (v < N) {
            float di = rsqrtf((float)dcnt[tl] + 1.0f);
            dinv[v] = di;
            xs[v] = di * x[v];
        }
    }
}

__global__ __launch_bounds__(ST) void k_l1k(const unsigned* __restrict__ pack1,
                                            const unsigned* __restrict__ gcur,
                                            const float* __restrict__ xs,
                                            const float* __restrict__ dinv,
                                            const float* __restrict__ W1,
                                            const float* __restrict__ b1,
                                            const float* __restrict__ W2,
                                            float* __restrict__ gs, int N) {
    __shared__ float acc[CW];
    const int b = blockIdx.x;
    const int t = threadIdx.x;
    acc[t] = 0.0f; acc[t + ST] = 0.0f;
    __syncthreads();
    unsigned s0 = (unsigned)b * CAP;
    unsigned s1 = min(gcur[b], s0 + (unsigned)CAP);
    unsigned n4 = (s1 - s0) >> 2;
    for (unsigned i = t; i < n4; i += ST) {
        uint4 p = reinterpret_cast<const uint4*>(pack1 + s0)[i];
        float v0 = xs[p.x >> CSHIFT];
        float v1 = xs[p.y >> CSHIFT];
        float v2 = xs[p.z >> CSHIFT];
        float v3 = xs[p.w >> CSHIFT];
        atomicAdd(&acc[p.x & CMASK], v0);
        atomicAdd(&acc[p.y & CMASK], v1);
        atomicAdd(&acc[p.z & CMASK], v2);
        atomicAdd(&acc[p.w & CMASK], v3);
    }
    unsigned i = s0 + (n4 << 2) + t;
    if (i < s1) {
        unsigned p = pack1[i];
        atomicAdd(&acc[p & CMASK], xs[p >> CSHIFT]);
    }
    __syncthreads();
#pragma unroll
    for (int j = 0; j < 2; ++j) {
        int tl = t + j * ST;
        int v = (b << CSHIFT) + tl;
        if (v < N) {
            float di = dinv[v];
            float tt = di * (acc[tl] + xs[v]);  // + self-loop
            float g = 0.0f;
#pragma unroll
            for (int jj = 0; jj < 16; ++jj) {
                float y = fmaxf(fmaf(W1[jj], tt, b1[jj]), 0.0f);
                g = fmaf(W2[2 * jj] - W2[2 * jj + 1], y, g);
            }
            gs[v] = di * g;
        }
    }
}

__global__ __launch_bounds__(ST) void k_l2k(const unsigned* __restrict__ pack1,
                                            const unsigned* __restrict__ gcur,
                                            const float* __restrict__ gs,
                                            const float* __restrict__ dinv,
                                            const float* __restrict__ b2,
                                            float* __restrict__ out, int N) {
    __shared__ float acc[CW];
    const int b = blockIdx.x;
    const int t = threadIdx.x;
    acc[t] = 0.0f; acc[t + ST] = 0.0f;
    __syncthreads();
    unsigned s0 = (unsigned)b * CAP;
    unsigned s1 = min(gcur[b], s0 + (unsigned)CAP);
    unsigned n4 = (s1 - s0) >> 2;
    for (unsigned i = t; i < n4; i += ST) {
        uint4 p = reinterpret_cast<const uint4*>(pack1 + s0)[i];
        float v0 = gs[p.x >> CSHIFT];
        float v1 = gs[p.y >> CSHIFT];
        float v2 = gs[p.z >> CSHIFT];
        float v3 = gs[p.w >> CSHIFT];
        atomicAdd(&acc[p.x & CMASK], v0);
        atomicAdd(&acc[p.y & CMASK], v1);
        atomicAdd(&acc[p.z & CMASK], v2);
        atomicAdd(&acc[p.w & CMASK], v3);
    }
    unsigned i = s0 + (n4 << 2) + t;
    if (i < s1) {
        unsigned p = pack1[i];
        atomicAdd(&acc[p & CMASK], gs[p >> CSHIFT]);
    }
    __syncthreads();
#pragma unroll
    for (int j = 0; j < 2; ++j) {
        int tl = t + j * ST;
        int v = (b << CSHIFT) + tl;
        if (v < N) {
            float diff = dinv[v] * (acc[tl] + gs[v]) + (b2[0] - b2[1]);
            float p0 = 1.0f / (1.0f + __expf(-diff));
            float2 o;
            o.x = p0;
            o.y = 1.0f - p0;
            reinterpret_cast<float2*>(out)[v] = o;
        }
    }
}

// ==================== generic fallback (R2 atomic path, any sizes) ====================
__global__ void k_zero_f(float* __restrict__ p, int n) {
    int i = blockIdx.x * blockDim.x + threadIdx.x;
    int v = i * 4;
    if (v + 3 < n) {
        reinterpret_cast<float4*>(p + v)[0] = make_float4(0.f, 0.f, 0.f, 0.f);
    } else {
        for (; v < n; ++v) p[v] = 0.0f;
    }
}
__global__ void k_deg_f(const int* __restrict__ col, float* __restrict__ deg, int E) {
    int i = blockIdx.x * blockDim.x + threadIdx.x;
    int e = i * 4;
    if (e + 3 < E) {
        int4 c = reinterpret_cast<const int4*>(col + e)[0];
        atomicAdd(deg + c.x, 1.0f); atomicAdd(deg + c.y, 1.0f);
        atomicAdd(deg + c.z, 1.0f); atomicAdd(deg + c.w, 1.0f);
    } else {
        for (; e < E; ++e) atomicAdd(deg + col[e], 1.0f);
    }
}
__global__ void k_node1_f(const float* __restrict__ x, float* __restrict__ degdinv,
                          float* __restrict__ xs, int N) {
    int v = blockIdx.x * blockDim.x + threadIdx.x;
    if (v < N) {
        float dinv = rsqrtf(degdinv[v] + 1.0f);
        degdinv[v] = dinv;
        xs[v] = dinv * x[v];
    }
}
__global__ void k_scat_f(const int* __restrict__ row, const int* __restrict__ col,
                         const float* __restrict__ src, float* __restrict__ acc, int E) {
    int i = blockIdx.x * blockDim.x + threadIdx.x;
    int e = i * 4;
    if (e + 3 < E) {
        int4 r = reinterpret_cast<const int4*>(row + e)[0];
        int4 c = reinterpret_cast<const int4*>(col + e)[0];
        float s0 = src[r.x], s1 = src[r.y], s2 = src[r.z], s3 = src[r.w];
        atomicAdd(acc + c.x, s0); atomicAdd(acc + c.y, s1);
        atomicAdd(acc + c.z, s2); atomicAdd(acc + c.w, s3);
    } else {
        for (; e < E; ++e) atomicAdd(acc + col[e], src[row[e]]);
    }
}
__global__ void k_mlp_f(const float* __restrict__ W1, const float* __restrict__ b1,
                        const float* __restrict__ W2, const float* __restrict__ dinv,
                        float* __restrict__ acc, float* __restrict__ xsgs, int N) {
    int v = blockIdx.x * blockDim.x + threadIdx.x;
    if (v < N) {
        float di = dinv[v];
        float t = di * (acc[v] + xsgs[v]);
        float g = 0.0f;
#pragma unroll
        for (int j = 0; j < 16; ++j) {
            float y = fmaxf(fmaf(W1[j], t, b1[j]), 0.0f);
            g = fmaf(W2[2 * j] - W2[2 * j + 1], y, g);
        }
        xsgs[v] = di * g;
        acc[v] = 0.0f;
    }
}
__global__ void k_out_f(const float* __restrict__ b2, const float* __restrict__ dinv,
                        const float* __restrict__ acc, const float* __restrict__ gs,
                        float* __restrict__ out, int N) {
    int v = blockIdx.x * blockDim.x + threadIdx.x;
    if (v < N) {
        float diff = dinv[v] * (acc[v] + gs[v]) + (b2[0] - b2[1]);
        float p0 = 1.0f / (1.0f + __expf(-diff));
        float2 o; o.x = p0; o.y = 1.0f - p0;
        reinterpret_cast<float2*>(out)[v] = o;
    }
}

extern "C" void kernel_launch(void* const* d_in, const int* in_sizes, int n_in,
                              void* d_out, int out_size, void* d_ws, size_t ws_size,
                              hipStream_t stream) {
    const float* x  = (const float*)d_in[0];
    const int* edge = (const int*)d_in[1];   // int64 in reference -> int32 in harness
    const float* W1 = (const float*)d_in[2];
    const float* b1 = (const float*)d_in[3];
    const float* W2 = (const float*)d_in[4];
    const float* b2 = (const float*)d_in[5];
    float* out = (float*)d_out;

    const int N = in_sizes[0];
    const int E = in_sizes[1] / 2;
    const int* row = edge;       // sources
    const int* col = edge + E;   // targets

    const int NC  = (N + CW - 1) >> CSHIFT;            // buckets (245)
    const int NBS = (E + EPB - 1) / EPB;               // sort blocks (489)

    // Capacity check: mean + 8 sigma must fit CAP.
    const double mean = (double)E / NC;
    const double slack = mean + 8.0 * __builtin_sqrt(mean > 1.0 ? mean : 1.0);
    // ws: pack1[NC*CAP] | gcur[NC] (ints) then dinv[N] | xs[N] | gs[N] (floats)
    const size_t need = ((size_t)NC * CAP + NC) * 4 + (size_t)3 * N * 4;

    if (NC <= NCMAX && N < (1 << 22) && slack < CAP && ws_size >= need) {
        unsigned* pack1 = (unsigned*)d_ws;
        unsigned* gcur  = pack1 + (size_t)NC * CAP;
        float* dinv     = (float*)(gcur + NC);
        float* xs       = dinv + N;
        float* gs       = xs + N;

        // Split launches: kernel boundary is the cheap device-wide sync on
        // gfx950 (cooperative grid.sync -> per-block device-scope L2 flushes
        // across non-coherent XCDs -> 3.5x regression, R8).
        k_init <<<1, 256, 0, stream>>>(gcur, NC);
        k_sortk<<<NBS, ST, 0, stream>>>(row, col, gcur, pack1, E, NC);
        k_degk <<<NC, ST, 0, stream>>>(pack1, gcur, x, dinv, xs, N);
        k_l1k  <<<NC, ST, 0, stream>>>(pack1, gcur, xs, dinv, W1, b1, W2, gs, N);
        k_l2k  <<<NC, ST, 0, stream>>>(pack1, gcur, gs, dinv, b2, out, N);
    } else {
        // generic fallback: R2 atomic-scatter path
        float* w0 = (float*)d_ws;
        float* w1 = w0 + N;
        float* w2 = w1 + N;
        const int nb = (N + 255) / 256;
        const int eb = ((E + 3) / 4 + 255) / 256;
        const int zb = ((2 * N + 3) / 4 + 255) / 256;
        k_zero_f <<<zb, 256, 0, stream>>>(w0, 2 * N);
        k_deg_f  <<<eb, 256, 0, stream>>>(col, w0, E);
        k_node1_f<<<nb, 256, 0, stream>>>(x, w0, w2, N);
        k_scat_f <<<eb, 256, 0, stream>>>(row, col, w2, w1, E);
        k_mlp_f  <<<nb, 256, 0, stream>>>(W1, b1, W2, w0, w1, w2, N);
        k_scat_f <<<eb, 256, 0, stream>>>(row, col, w2, w1, E);
        k_out_f  <<<nb, 256, 0, stream>>>(b2, w0, w1, w2, out, N);
    }
}

// Round 11
// 173.785 us; speedup vs baseline: 3.9360x; 1.0534x over previous
//
#include <hip/hip_runtime.h>

#define ST 512            // sort block threads (8 waves)
#define PT 20             // edges per sort thread
#define EPB (ST * PT)     // 10240 edges per sort block
#define CSHIFT 10         // bucket = col >> 10 (width 1024)
#define CMASK 1023u
#define CW 1024           // bucket width == gather-kernel threads
#define NCMAX 256         // max buckets supported by sort LDS arrays
#define CAP 24576         // slots/bucket (mean 20408, sigma ~143 -> 29 sigma slack)

// ==================== LDS-staged counting sort ====================
// pack1 = (row << 10) | (col & 1023)   [requires N < 2^22]
// bucket b owns pack1[b*CAP .. gcur[b]) after k_sortk.

__global__ void k_init(unsigned* __restrict__ gcur, int NC) {
    for (int b = threadIdx.x; b < NC; b += blockDim.x)
        gcur[b] = (unsigned)b * CAP;
}

__global__ __launch_bounds__(ST) void k_sortk(const int* __restrict__ row,
                                              const int* __restrict__ col,
                                              unsigned* __restrict__ gcur,
                                              unsigned* __restrict__ pack1,
                                              int E, int NC) {
    __shared__ unsigned loff[NCMAX + 1];   // hist -> exclusive offsets
    __shared__ unsigned gbase[NCMAX];      // per-bucket global reservation base
    __shared__ unsigned cur[NCMAX];        // staging placement cursors
    __shared__ unsigned staging[EPB];      // 40 KB packed edges, bucket-grouped

    const int t = threadIdx.x;
    for (int i = t; i <= NC; i += ST) loff[i] = 0;
    __syncthreads();

    const int base = blockIdx.x * EPB;
    int c[PT];

    // ---- load col (kept in registers), histogram into loff[b+1] ----
#pragma unroll
    for (int k = 0; k < PT / 4; ++k) {
        int e = base + (k * ST + t) * 4;
        int4 cc;
        if (e + 3 < E) {
            cc = *reinterpret_cast<const int4*>(col + e);
        } else {
            cc.x = (e     < E) ? col[e]     : -1;
            cc.y = (e + 1 < E) ? col[e + 1] : -1;
            cc.z = (e + 2 < E) ? col[e + 2] : -1;
            cc.w = (e + 3 < E) ? col[e + 3] : -1;
        }
        c[4 * k] = cc.x; c[4 * k + 1] = cc.y; c[4 * k + 2] = cc.z; c[4 * k + 3] = cc.w;
    }
#pragma unroll
    for (int k = 0; k < PT; ++k)
        if (c[k] >= 0) atomicAdd(&loff[((unsigned)c[k] >> CSHIFT) + 1], 1u);
    __syncthreads();

    // ---- inclusive scan of loff[0..NC] ----
    for (int o = 1; o <= NC; o <<= 1) {
        unsigned v = 0;
        if (t <= NC && t >= o) v = loff[t - o];
        __syncthreads();
        if (t <= NC) loff[t] += v;
        __syncthreads();
    }

    // ---- per-bucket contiguous global reservation ----
    if (t < NC) {
        unsigned cb = loff[t + 1] - loff[t];
        gbase[t] = atomicAdd(&gcur[t], cb);
        cur[t] = loff[t];
    }
    __syncthreads();

    // ---- place packed edges into LDS staging (bucket-grouped) ----
#pragma unroll
    for (int k = 0; k < PT / 4; ++k) {
        int e = base + (k * ST + t) * 4;
        int4 rr = make_int4(0, 0, 0, 0);
        if (e + 3 < E) {
            rr = *reinterpret_cast<const int4*>(row + e);
        } else {
            rr.x = (e     < E) ? row[e]     : 0;
            rr.y = (e + 1 < E) ? row[e + 1] : 0;
            rr.z = (e + 2 < E) ? row[e + 2] : 0;
            rr.w = (e + 3 < E) ? row[e + 3] : 0;
        }
        int rl[4] = {rr.x, rr.y, rr.z, rr.w};
#pragma unroll
        for (int j = 0; j < 4; ++j) {
            int cc = c[4 * k + j];
            if (cc >= 0) {
                unsigned b = (unsigned)cc >> CSHIFT;
                unsigned p = atomicAdd(&cur[b], 1u);
                staging[p] = ((unsigned)rl[j] << CSHIFT) | ((unsigned)cc & CMASK);
            }
        }
    }
    __syncthreads();

    // ---- coalesced copy-out: one wave per bucket (broadcast LDS reads,
    //      consecutive global stores; no per-element search chains) ----
    const int wave = t >> 6;
    const int lane = t & 63;
    for (int b = wave; b < NC; b += ST / 64) {
        unsigned lo = loff[b];
        unsigned hi = loff[b + 1];
        unsigned gb = gbase[b];
        unsigned lim = (unsigned)(b + 1) * CAP;
        for (unsigned i = lo + lane; i < hi; i += 64) {
            unsigned pos = gb + (i - lo);
            if (pos < lim)                      // 29-sigma overflow guard
                pack1[pos] = staging[i];
        }
    }
}

// ==================== per-bucket gather kernels (1024 threads, 1 node/thread) ====================

__global__ __launch_bounds__(CW) void k_degk(const unsigned* __restrict__ pack1,
                                             const unsigned* __restrict__ gcur,
                                             const float* __restrict__ x,
                                             float* __restrict__ dinv, float* __restrict__ xs,
                                             int N) {
    __shared__ unsigned dcnt[CW];
    const int b = blockIdx.x;
    const int t = threadIdx.x;
    dcnt[t] = 0;
    __syncthreads();
    unsigned s0 = (unsigned)b * CAP;
    unsigned s1 = min(gcur[b], s0 + (unsigned)CAP);
    unsigned n4 = (s1 - s0) >> 2;
    for (unsigned i = t; i < n4; i += CW) {
        uint4 p = reinterpret_cast<const uint4*>(pack1 + s0)[i];
        atomicAdd(&dcnt[p.x & CMASK], 1u);
        atomicAdd(&dcnt[p.y & CMASK], 1u);
        atomicAdd(&dcnt[p.z & CMASK], 1u);
        atomicAdd(&dcnt[p.w & CMASK], 1u);
    }
    unsigned i = s0 + (n4 << 2) + t;
    if (i < s1) atomicAdd(&dcnt[pack1[i] & CMASK], 1u);
    __syncthreads();
    int v = (b << CSHIFT) + t;
    if (v < N) {
        float di = rsqrtf((float)dcnt[t] + 1.0f);
        dinv[v] = di;
        xs[v] = di * x[v];
    }
}

__global__ __launch_bounds__(CW) void k_l1k(const unsigned* __restrict__ pack1,
                                            const unsigned* __restrict__ gcur,
                                            const float* __restrict__ xs,
                                            const float* __restrict__ dinv,
                                            const float* __restrict__ W1,
                                            const float* __restrict__ b1,
                                            const float* __restrict__ W2,
                                            float* __restrict__ gs, int N) {
    __shared__ float acc[CW];
    const int b = blockIdx.x;
    const int t = threadIdx.x;
    acc[t] = 0.0f;
    __syncthreads();
    unsigned s0 = (unsigned)b * CAP;
    unsigned s1 = min(gcur[b], s0 + (unsigned)CAP);
    unsigned n4 = (s1 - s0) >> 2;
    for (unsigned i = t; i < n4; i += CW) {
        uint4 p = reinterpret_cast<const uint4*>(pack1 + s0)[i];
        float v0 = xs[p.x >> CSHIFT];
        float v1 = xs[p.y >> CSHIFT];
        float v2 = xs[p.z >> CSHIFT];
        float v3 = xs[p.w >> CSHIFT];
        atomicAdd(&acc[p.x & CMASK], v0);
        atomicAdd(&acc[p.y & CMASK], v1);
        atomicAdd(&acc[p.z & CMASK], v2);
        atomicAdd(&acc[p.w & CMASK], v3);
    }
    unsigned i = s0 + (n4 << 2) + t;
    if (i < s1) {
        unsigned p = pack1[i];
        atomicAdd(&acc[p & CMASK], xs[p >> CSHIFT]);
    }
    __syncthreads();
    int v = (b << CSHIFT) + t;
    if (v < N) {
        float di = dinv[v];
        float tt = di * (acc[t] + xs[v]);  // + self-loop
        float g = 0.0f;
#pragma unroll
        for (int jj = 0; jj < 16; ++jj) {
            float y = fmaxf(fmaf(W1[jj], tt, b1[jj]), 0.0f);
            g = fmaf(W2[2 * jj] - W2[2 * jj + 1], y, g);
        }
        gs[v] = di * g;
    }
}

__global__ __launch_bounds__(CW) void k_l2k(const unsigned* __restrict__ pack1,
                                            const unsigned* __restrict__ gcur,
                                            const float* __restrict__ gs,
                                            const float* __restrict__ dinv,
                                            const float* __restrict__ b2,
                                            float* __restrict__ out, int N) {
    __shared__ float acc[CW];
    const int b = blockIdx.x;
    const int t = threadIdx.x;
    acc[t] = 0.0f;
    __syncthreads();
    unsigned s0 = (unsigned)b * CAP;
    unsigned s1 = min(gcur[b], s0 + (unsigned)CAP);
    unsigned n4 = (s1 - s0) >> 2;
    for (unsigned i = t; i < n4; i += CW) {
        uint4 p = reinterpret_cast<const uint4*>(pack1 + s0)[i];
        float v0 = gs[p.x >> CSHIFT];
        float v1 = gs[p.y >> CSHIFT];
        float v2 = gs[p.z >> CSHIFT];
        float v3 = gs[p.w >> CSHIFT];
        atomicAdd(&acc[p.x & CMASK], v0);
        atomicAdd(&acc[p.y & CMASK], v1);
        atomicAdd(&acc[p.z & CMASK], v2);
        atomicAdd(&acc[p.w & CMASK], v3);
    }
    unsigned i = s0 + (n4 << 2) + t;
    if (i < s1) {
        unsigned p = pack1[i];
        atomicAdd(&acc[p & CMASK], gs[p >> CSHIFT]);
    }
    __syncthreads();
    int v = (b << CSHIFT) + t;
    if (v < N) {
        float diff = dinv[v] * (acc[t] + gs[v]) + (b2[0] - b2[1]);
        float p0 = 1.0f / (1.0f + __expf(-diff));
        float2 o;
        o.x = p0;
        o.y = 1.0f - p0;
        reinterpret_cast<float2*>(out)[v] = o;
    }
}

// ==================== generic fallback (R2 atomic path, any sizes) ====================
__global__ void k_zero_f(float* __restrict__ p, int n) {
    int i = blockIdx.x * blockDim.x + threadIdx.x;
    int v = i * 4;
    if (v + 3 < n) {
        reinterpret_cast<float4*>(p + v)[0] = make_float4(0.f, 0.f, 0.f, 0.f);
    } else {
        for (; v < n; ++v) p[v] = 0.0f;
    }
}
__global__ void k_deg_f(const int* __restrict__ col, float* __restrict__ deg, int E) {
    int i = blockIdx.x * blockDim.x + threadIdx.x;
    int e = i * 4;
    if (e + 3 < E) {
        int4 c = reinterpret_cast<const int4*>(col + e)[0];
        atomicAdd(deg + c.x, 1.0f); atomicAdd(deg + c.y, 1.0f);
        atomicAdd(deg + c.z, 1.0f); atomicAdd(deg + c.w, 1.0f);
    } else {
        for (; e < E; ++e) atomicAdd(deg + col[e], 1.0f);
    }
}
__global__ void k_node1_f(const float* __restrict__ x, float* __restrict__ degdinv,
                          float* __restrict__ xs, int N) {
    int v = blockIdx.x * blockDim.x + threadIdx.x;
    if (v < N) {
        float dinv = rsqrtf(degdinv[v] + 1.0f);
        degdinv[v] = dinv;
        xs[v] = dinv * x[v];
    }
}
__global__ void k_scat_f(const int* __restrict__ row, const int* __restrict__ col,
                         const float* __restrict__ src, float* __restrict__ acc, int E) {
    int i = blockIdx.x * blockDim.x + threadIdx.x;
    int e = i * 4;
    if (e + 3 < E) {
        int4 r = reinterpret_cast<const int4*>(row + e)[0];
        int4 c = reinterpret_cast<const int4*>(col + e)[0];
        float s0 = src[r.x], s1 = src[r.y], s2 = src[r.z], s3 = src[r.w];
        atomicAdd(acc + c.x, s0); atomicAdd(acc + c.y, s1);
        atomicAdd(acc + c.z, s2); atomicAdd(acc + c.w, s3);
    } else {
        for (; e < E; ++e) atomicAdd(acc + col[e], src[row[e]]);
    }
}
__global__ void k_mlp_f(const float* __restrict__ W1, const float* __restrict__ b1,
                        const float* __restrict__ W2, const float* __restrict__ dinv,
                        float* __restrict__ acc, float* __restrict__ xsgs, int N) {
    int v = blockIdx.x * blockDim.x + threadIdx.x;
    if (v < N) {
        float di = dinv[v];
        float t = di * (acc[v] + xsgs[v]);
        float g = 0.0f;
#pragma unroll
        for (int j = 0; j < 16; ++j) {
            float y = fmaxf(fmaf(W1[j], t, b1[j]), 0.0f);
            g = fmaf(W2[2 * j] - W2[2 * j + 1], y, g);
        }
        xsgs[v] = di * g;
        acc[v] = 0.0f;
    }
}
__global__ void k_out_f(const float* __restrict__ b2, const float* __restrict__ dinv,
                        const float* __restrict__ acc, const float* __restrict__ gs,
                        float* __restrict__ out, int N) {
    int v = blockIdx.x * blockDim.x + threadIdx.x;
    if (v < N) {
        float diff = dinv[v] * (acc[v] + gs[v]) + (b2[0] - b2[1]);
        float p0 = 1.0f / (1.0f + __expf(-diff));
        float2 o; o.x = p0; o.y = 1.0f - p0;
        reinterpret_cast<float2*>(out)[v] = o;
    }
}

extern "C" void kernel_launch(void* const* d_in, const int* in_sizes, int n_in,
                              void* d_out, int out_size, void* d_ws, size_t ws_size,
                              hipStream_t stream) {
    const float* x  = (const float*)d_in[0];
    const int* edge = (const int*)d_in[1];   // int64 in reference -> int32 in harness
    const float* W1 = (const float*)d_in[2];
    const float* b1 = (const float*)d_in[3];
    const float* W2 = (const float*)d_in[4];
    const float* b2 = (const float*)d_in[5];
    float* out = (float*)d_out;

    const int N = in_sizes[0];
    const int E = in_sizes[1] / 2;
    const int* row = edge;       // sources
    const int* col = edge + E;   // targets

    const int NC  = (N + CW - 1) >> CSHIFT;            // buckets (245)
    const int NBS = (E + EPB - 1) / EPB;               // sort blocks (489)

    // Capacity check: mean + 8 sigma must fit CAP.
    const double mean = (double)E / NC;
    const double slack = mean + 8.0 * __builtin_sqrt(mean > 1.0 ? mean : 1.0);
    // ws: pack1[NC*CAP] | gcur[NC] (ints) then dinv[N] | xs[N] | gs[N] (floats)
    const size_t need = ((size_t)NC * CAP + NC) * 4 + (size_t)3 * N * 4;

    if (NC <= NCMAX && N < (1 << 22) && slack < CAP && ws_size >= need) {
        unsigned* pack1 = (unsigned*)d_ws;
        unsigned* gcur  = pack1 + (size_t)NC * CAP;
        float* dinv     = (float*)(gcur + NC);
        float* xs       = dinv + N;
        float* gs       = xs + N;

        // Split launches: kernel boundary is the cheap device-wide sync on
        // gfx950 (cooperative grid.sync -> per-block device-scope L2 flushes
        // across non-coherent XCDs -> 3.5x regression, R8).
        k_init <<<1, 256, 0, stream>>>(gcur, NC);
        k_sortk<<<NBS, ST, 0, stream>>>(row, col, gcur, pack1, E, NC);
        k_degk <<<NC, CW, 0, stream>>>(pack1, gcur, x, dinv, xs, N);
        k_l1k  <<<NC, CW, 0, stream>>>(pack1, gcur, xs, dinv, W1, b1, W2, gs, N);
        k_l2k  <<<NC, CW, 0, stream>>>(pack1, gcur, gs, dinv, b2, out, N);
    } else {
        // generic fallback: R2 atomic-scatter path
        float* w0 = (float*)d_ws;
        float* w1 = w0 + N;
        float* w2 = w1 + N;
        const int nb = (N + 255) / 256;
        const int eb = ((E + 3) / 4 + 255) / 256;
        const int zb = ((2 * N + 3) / 4 + 255) / 256;
        k_zero_f <<<zb, 256, 0, stream>>>(w0, 2 * N);
        k_deg_f  <<<eb, 256, 0, stream>>>(col, w0, E);
        k_node1_f<<<nb, 256, 0, stream>>>(x, w0, w2, N);
        k_scat_f <<<eb, 256, 0, stream>>>(row, col, w2, w1, E);
        k_mlp_f  <<<nb, 256, 0, stream>>>(W1, b1, W2, w0, w1, w2, N);
        k_scat_f <<<eb, 256, 0, stream>>>(row, col, w2, w1, E);
        k_out_f  <<<nb, 256, 0, stream>>>(b2, w0, w1, w2, out, N);
    }
}

// Round 12
// 169.559 us; speedup vs baseline: 4.0341x; 1.0249x over previous
//
#include <hip/hip_runtime.h>

#define ST 512            // sort block threads (8 waves)
#define PT 24             // edges per sort thread
#define EPB (ST * PT)     // 12288 edges per sort block
#define CSHIFT 10         // bucket = col >> 10 (width 1024)
#define CMASK 1023u
#define CW 1024           // bucket width == gather-kernel threads
#define NCMAX 255         // max buckets (wave-scan handles NC+1 <= 256 entries)
#define CAP 24576         // slots/bucket (mean 20408, sigma ~143 -> 29 sigma slack)

// ==================== LDS-staged counting sort ====================
// pack1 = (row << 10) | (col & 1023)   [requires N < 2^22]
// bucket b owns pack1[b*CAP .. gcur[b]) after k_sortk.

__global__ void k_init(unsigned* __restrict__ gcur, int NC) {
    for (int b = threadIdx.x; b < NC; b += blockDim.x)
        gcur[b] = (unsigned)b * CAP;
}

__global__ __launch_bounds__(ST) void k_sortk(const int* __restrict__ row,
                                              const int* __restrict__ col,
                                              unsigned* __restrict__ gcur,
                                              unsigned* __restrict__ pack1,
                                              int E, int NC) {
    __shared__ unsigned loff[NCMAX + 2];   // hist -> offsets (inclusive scan)
    __shared__ unsigned gbase[NCMAX + 1];  // per-bucket global reservation base
    __shared__ unsigned cur[NCMAX + 1];    // staging placement cursors
    __shared__ unsigned staging[EPB];      // 48 KB packed edges, bucket-grouped

    const int t = threadIdx.x;
    for (int i = t; i <= NC; i += ST) loff[i] = 0;
    __syncthreads();

    const int base = blockIdx.x * EPB;
    int c[PT];

    // ---- load col (kept in registers), histogram into loff[b+1] ----
#pragma unroll
    for (int k = 0; k < PT / 4; ++k) {
        int e = base + (k * ST + t) * 4;
        int4 cc;
        if (e + 3 < E) {
            cc = *reinterpret_cast<const int4*>(col + e);
        } else {
            cc.x = (e     < E) ? col[e]     : -1;
            cc.y = (e + 1 < E) ? col[e + 1] : -1;
            cc.z = (e + 2 < E) ? col[e + 2] : -1;
            cc.w = (e + 3 < E) ? col[e + 3] : -1;
        }
        c[4 * k] = cc.x; c[4 * k + 1] = cc.y; c[4 * k + 2] = cc.z; c[4 * k + 3] = cc.w;
    }
#pragma unroll
    for (int k = 0; k < PT; ++k)
        if (c[k] >= 0) atomicAdd(&loff[((unsigned)c[k] >> CSHIFT) + 1], 1u);
    __syncthreads();

    // ---- wave-0 shuffle scan of loff[0..NC] (2 barriers, no LDS ping-pong) ----
    if (t < 64) {
        unsigned v[4];
        unsigned ls = 0;
#pragma unroll
        for (int k = 0; k < 4; ++k) {
            int idx = t * 4 + k;
            v[k] = (idx <= NC) ? loff[idx] : 0;
            ls += v[k];
        }
        unsigned sc = ls;
#pragma unroll
        for (int d = 1; d < 64; d <<= 1) {
            unsigned n = __shfl_up(sc, d, 64);
            if (t >= d) sc += n;
        }
        unsigned run = sc - ls;   // exclusive offset for this lane's 4 entries
#pragma unroll
        for (int k = 0; k < 4; ++k) {
            int idx = t * 4 + k;
            run += v[k];
            if (idx <= NC) loff[idx] = run;   // inclusive scan result
        }
    }
    __syncthreads();

    // ---- per-bucket contiguous global reservation ----
    if (t < NC) {
        unsigned cb = loff[t + 1] - loff[t];
        gbase[t] = atomicAdd(&gcur[t], cb);
        cur[t] = loff[t];
    }
    __syncthreads();

    // ---- place packed edges into LDS staging (bucket-grouped) ----
#pragma unroll
    for (int k = 0; k < PT / 4; ++k) {
        int e = base + (k * ST + t) * 4;
        int4 rr = make_int4(0, 0, 0, 0);
        if (e + 3 < E) {
            rr = *reinterpret_cast<const int4*>(row + e);
        } else {
            rr.x = (e     < E) ? row[e]     : 0;
            rr.y = (e + 1 < E) ? row[e + 1] : 0;
            rr.z = (e + 2 < E) ? row[e + 2] : 0;
            rr.w = (e + 3 < E) ? row[e + 3] : 0;
        }
        int rl[4] = {rr.x, rr.y, rr.z, rr.w};
#pragma unroll
        for (int j = 0; j < 4; ++j) {
            int cc = c[4 * k + j];
            if (cc >= 0) {
                unsigned b = (unsigned)cc >> CSHIFT;
                unsigned p = atomicAdd(&cur[b], 1u);
                staging[p] = ((unsigned)rl[j] << CSHIFT) | ((unsigned)cc & CMASK);
            }
        }
    }
    __syncthreads();

    // ---- coalesced copy-out: one wave per bucket ----
    const int wave = t >> 6;
    const int lane = t & 63;
    for (int b = wave; b < NC; b += ST / 64) {
        unsigned lo = loff[b];
        unsigned hi = loff[b + 1];
        unsigned gb = gbase[b];
        unsigned lim = (unsigned)(b + 1) * CAP;
        for (unsigned i = lo + lane; i < hi; i += 64) {
            unsigned pos = gb + (i - lo);
            if (pos < lim)                      // 29-sigma overflow guard
                pack1[pos] = staging[i];
        }
    }
}

// ==================== per-bucket gather kernels (1024 threads, 1 node/thread) ====================

__global__ __launch_bounds__(CW) void k_degk(const unsigned* __restrict__ pack1,
                                             const unsigned* __restrict__ gcur,
                                             const float* __restrict__ x,
                                             float* __restrict__ dinv, float* __restrict__ xs,
                                             int N) {
    __shared__ unsigned dcnt[CW];
    const int b = blockIdx.x;
    const int t = threadIdx.x;
    dcnt[t] = 0;
    __syncthreads();
    unsigned s0 = (unsigned)b * CAP;
    unsigned s1 = min(gcur[b], s0 + (unsigned)CAP);
    unsigned n4 = (s1 - s0) >> 2;
    for (unsigned i = t; i < n4; i += CW) {
        uint4 p = reinterpret_cast<const uint4*>(pack1 + s0)[i];
        atomicAdd(&dcnt[p.x & CMASK], 1u);
        atomicAdd(&dcnt[p.y & CMASK], 1u);
        atomicAdd(&dcnt[p.z & CMASK], 1u);
        atomicAdd(&dcnt[p.w & CMASK], 1u);
    }
    unsigned i = s0 + (n4 << 2) + t;
    if (i < s1) atomicAdd(&dcnt[pack1[i] & CMASK], 1u);
    __syncthreads();
    int v = (b << CSHIFT) + t;
    if (v < N) {
        float di = rsqrtf((float)dcnt[t] + 1.0f);
        dinv[v] = di;
        xs[v] = di * x[v];
    }
}

__global__ __launch_bounds__(CW) void k_l1k(const unsigned* __restrict__ pack1,
                                            const unsigned* __restrict__ gcur,
                                            const float* __restrict__ xs,
                                            const float* __restrict__ dinv,
                                            const float* __restrict__ W1,
                                            const float* __restrict__ b1,
                                            const float* __restrict__ W2,
                                            float* __restrict__ gs, int N) {
    __shared__ float acc[CW];
    const int b = blockIdx.x;
    const int t = threadIdx.x;
    acc[t] = 0.0f;
    __syncthreads();
    unsigned s0 = (unsigned)b * CAP;
    unsigned s1 = min(gcur[b], s0 + (unsigned)CAP);
    unsigned n4 = (s1 - s0) >> 2;
    for (unsigned i = t; i < n4; i += CW) {
        uint4 p = reinterpret_cast<const uint4*>(pack1 + s0)[i];
        float v0 = xs[p.x >> CSHIFT];
        float v1 = xs[p.y >> CSHIFT];
        float v2 = xs[p.z >> CSHIFT];
        float v3 = xs[p.w >> CSHIFT];
        atomicAdd(&acc[p.x & CMASK], v0);
        atomicAdd(&acc[p.y & CMASK], v1);
        atomicAdd(&acc[p.z & CMASK], v2);
        atomicAdd(&acc[p.w & CMASK], v3);
    }
    unsigned i = s0 + (n4 << 2) + t;
    if (i < s1) {
        unsigned p = pack1[i];
        atomicAdd(&acc[p & CMASK], xs[p >> CSHIFT]);
    }
    __syncthreads();
    int v = (b << CSHIFT) + t;
    if (v < N) {
        float di = dinv[v];
        float tt = di * (acc[t] + xs[v]);  // + self-loop
        float g = 0.0f;
#pragma unroll
        for (int jj = 0; jj < 16; ++jj) {
            float y = fmaxf(fmaf(W1[jj], tt, b1[jj]), 0.0f);
            g = fmaf(W2[2 * jj] - W2[2 * jj + 1], y, g);
        }
        gs[v] = di * g;
    }
}

__global__ __launch_bounds__(CW) void k_l2k(const unsigned* __restrict__ pack1,
                                            const unsigned* __restrict__ gcur,
                                            const float* __restrict__ gs,
                                            const float* __restrict__ dinv,
                                            const float* __restrict__ b2,
                                            float* __restrict__ out, int N) {
    __shared__ float acc[CW];
    const int b = blockIdx.x;
    const int t = threadIdx.x;
    acc[t] = 0.0f;
    __syncthreads();
    unsigned s0 = (unsigned)b * CAP;
    unsigned s1 = min(gcur[b], s0 + (unsigned)CAP);
    unsigned n4 = (s1 - s0) >> 2;
    for (unsigned i = t; i < n4; i += CW) {
        uint4 p = reinterpret_cast<const uint4*>(pack1 + s0)[i];
        float v0 = gs[p.x >> CSHIFT];
        float v1 = gs[p.y >> CSHIFT];
        float v2 = gs[p.z >> CSHIFT];
        float v3 = gs[p.w >> CSHIFT];
        atomicAdd(&acc[p.x & CMASK], v0);
        atomicAdd(&acc[p.y & CMASK], v1);
        atomicAdd(&acc[p.z & CMASK], v2);
        atomicAdd(&acc[p.w & CMASK], v3);
    }
    unsigned i = s0 + (n4 << 2) + t;
    if (i < s1) {
        unsigned p = pack1[i];
        atomicAdd(&acc[p & CMASK], gs[p >> CSHIFT]);
    }
    __syncthreads();
    int v = (b << CSHIFT) + t;
    if (v < N) {
        float diff = dinv[v] * (acc[t] + gs[v]) + (b2[0] - b2[1]);
        float p0 = 1.0f / (1.0f + __expf(-diff));
        float2 o;
        o.x = p0;
        o.y = 1.0f - p0;
        reinterpret_cast<float2*>(out)[v] = o;
    }
}

// ==================== generic fallback (R2 atomic path, any sizes) ====================
__global__ void k_zero_f(float* __restrict__ p, int n) {
    int i = blockIdx.x * blockDim.x + threadIdx.x;
    int v = i * 4;
    if (v + 3 < n) {
        reinterpret_cast<float4*>(p + v)[0] = make_float4(0.f, 0.f, 0.f, 0.f);
    } else {
        for (; v < n; ++v) p[v] = 0.0f;
    }
}
__global__ void k_deg_f(const int* __restrict__ col, float* __restrict__ deg, int E) {
    int i = blockIdx.x * blockDim.x + threadIdx.x;
    int e = i * 4;
    if (e + 3 < E) {
        int4 c = reinterpret_cast<const int4*>(col + e)[0];
        atomicAdd(deg + c.x, 1.0f); atomicAdd(deg + c.y, 1.0f);
        atomicAdd(deg + c.z, 1.0f); atomicAdd(deg + c.w, 1.0f);
    } else {
        for (; e < E; ++e) atomicAdd(deg + col[e], 1.0f);
    }
}
__global__ void k_node1_f(const float* __restrict__ x, float* __restrict__ degdinv,
                          float* __restrict__ xs, int N) {
    int v = blockIdx.x * blockDim.x + threadIdx.x;
    if (v < N) {
        float dinv = rsqrtf(degdinv[v] + 1.0f);
        degdinv[v] = dinv;
        xs[v] = dinv * x[v];
    }
}
__global__ void k_scat_f(const int* __restrict__ row, const int* __restrict__ col,
                         const float* __restrict__ src, float* __restrict__ acc, int E) {
    int i = blockIdx.x * blockDim.x + threadIdx.x;
    int e = i * 4;
    if (e + 3 < E) {
        int4 r = reinterpret_cast<const int4*>(row + e)[0];
        int4 c = reinterpret_cast<const int4*>(col + e)[0];
        float s0 = src[r.x], s1 = src[r.y], s2 = src[r.z], s3 = src[r.w];
        atomicAdd(acc + c.x, s0); atomicAdd(acc + c.y, s1);
        atomicAdd(acc + c.z, s2); atomicAdd(acc + c.w, s3);
    } else {
        for (; e < E; ++e) atomicAdd(acc + col[e], src[row[e]]);
    }
}
__global__ void k_mlp_f(const float* __restrict__ W1, const float* __restrict__ b1,
                        const float* __restrict__ W2, const float* __restrict__ dinv,
                        float* __restrict__ acc, float* __restrict__ xsgs, int N) {
    int v = blockIdx.x * blockDim.x + threadIdx.x;
    if (v < N) {
        float di = dinv[v];
        float t = di * (acc[v] + xsgs[v]);
        float g = 0.0f;
#pragma unroll
        for (int j = 0; j < 16; ++j) {
            float y = fmaxf(fmaf(W1[j], t, b1[j]), 0.0f);
            g = fmaf(W2[2 * j] - W2[2 * j + 1], y, g);
        }
        xsgs[v] = di * g;
        acc[v] = 0.0f;
    }
}
__global__ void k_out_f(const float* __restrict__ b2, const float* __restrict__ dinv,
                        const float* __restrict__ acc, const float* __restrict__ gs,
                        float* __restrict__ out, int N) {
    int v = blockIdx.x * blockDim.x + threadIdx.x;
    if (v < N) {
        float diff = dinv[v] * (acc[v] + gs[v]) + (b2[0] - b2[1]);
        float p0 = 1.0f / (1.0f + __expf(-diff));
        float2 o; o.x = p0; o.y = 1.0f - p0;
        reinterpret_cast<float2*>(out)[v] = o;
    }
}

extern "C" void kernel_launch(void* const* d_in, const int* in_sizes, int n_in,
                              void* d_out, int out_size, void* d_ws, size_t ws_size,
                              hipStream_t stream) {
    const float* x  = (const float*)d_in[0];
    const int* edge = (const int*)d_in[1];   // int64 in reference -> int32 in harness
    const float* W1 = (const float*)d_in[2];
    const float* b1 = (const float*)d_in[3];
    const float* W2 = (const float*)d_in[4];
    const float* b2 = (const float*)d_in[5];
    float* out = (float*)d_out;

    const int N = in_sizes[0];
    const int E = in_sizes[1] / 2;
    const int* row = edge;       // sources
    const int* col = edge + E;   // targets

    const int NC  = (N + CW - 1) >> CSHIFT;            // buckets (245)
    const int NBS = (E + EPB - 1) / EPB;               // sort blocks (407)

    // Capacity check: mean + 8 sigma must fit CAP.
    const double mean = (double)E / NC;
    const double slack = mean + 8.0 * __builtin_sqrt(mean > 1.0 ? mean : 1.0);
    // ws: pack1[NC*CAP] | gcur[NC] (ints) then dinv[N] | xs[N] | gs[N] (floats)
    const size_t need = ((size_t)NC * CAP + NC) * 4 + (size_t)3 * N * 4;

    if (NC <= NCMAX && N < (1 << 22) && slack < CAP && ws_size >= need) {
        unsigned* pack1 = (unsigned*)d_ws;
        unsigned* gcur  = pack1 + (size_t)NC * CAP;
        float* dinv     = (float*)(gcur + NC);
        float* xs       = dinv + N;
        float* gs       = xs + N;

        // Split launches: kernel boundary is the cheap device-wide sync on
        // gfx950 (cooperative grid.sync -> per-block device-scope L2 flushes
        // across non-coherent XCDs -> 3.5x regression, R8).
        k_init <<<1, 256, 0, stream>>>(gcur, NC);
        k_sortk<<<NBS, ST, 0, stream>>>(row, col, gcur, pack1, E, NC);
        k_degk <<<NC, CW, 0, stream>>>(pack1, gcur, x, dinv, xs, N);
        k_l1k  <<<NC, CW, 0, stream>>>(pack1, gcur, xs, dinv, W1, b1, W2, gs, N);
        k_l2k  <<<NC, CW, 0, stream>>>(pack1, gcur, gs, dinv, b2, out, N);
    } else {
        // generic fallback: R2 atomic-scatter path
        float* w0 = (float*)d_ws;
        float* w1 = w0 + N;
        float* w2 = w1 + N;
        const int nb = (N + 255) / 256;
        const int eb = ((E + 3) / 4 + 255) / 256;
        const int zb = ((2 * N + 3) / 4 + 255) / 256;
        k_zero_f <<<zb, 256, 0, stream>>>(w0, 2 * N);
        k_deg_f  <<<eb, 256, 0, stream>>>(col, w0, E);
        k_node1_f<<<nb, 256, 0, stream>>>(x, w0, w2, N);
        k_scat_f <<<eb, 256, 0, stream>>>(row, col, w2, w1, E);
        k_mlp_f  <<<nb, 256, 0, stream>>>(W1, b1, W2, w0, w1, w2, N);
        k_scat_f <<<eb, 256, 0, stream>>>(row, col, w2, w1, E);
        k_out_f  <<<nb, 256, 0, stream>>>(b2, w0, w1, w2, out, N);
    }
}